// Round 1
// baseline (1138.079 us; speedup 1.0000x reference)
//
#include <hip/hip_runtime.h>
#include <math.h>

// Sizes (fixed by the problem)
#define B 32
#define D 1024
#define H 16
#define DH 64
#define TCTX 4096
#define NCHUNK 4          // attn T-chunks of 1024
#define CHUNK 1024

// ---------------- Kernel A: fused q/k/v projections (split-K, atomics) ----
// grid (12, 16): x = column-chunk over 3*1024 outputs, y = K-chunk over 1024.
__global__ __launch_bounds__(256) void proj_qkv(
    const float* __restrict__ x,
    const float* __restrict__ Wq, const float* __restrict__ bq,
    const float* __restrict__ Wk, const float* __restrict__ bk,
    const float* __restrict__ Wv, const float* __restrict__ bv,
    float* __restrict__ qs, float* __restrict__ kn, float* __restrict__ vn)
{
    const int jc  = blockIdx.x;           // 0..11
    const int kc  = blockIdx.y;           // 0..15
    const int tid = threadIdx.x;
    const int jj  = jc * 256 + tid;       // 0..3071
    const int p   = jj >> 10;             // 0=q,1=k,2=v (block-uniform)
    const int col = jj & 1023;            // h*64+dh

    const float* W    = (p == 0) ? Wq : (p == 1) ? Wk : Wv;
    const float* bias = (p == 0) ? bq : (p == 1) ? bk : bv;
    float*       dst  = (p == 0) ? qs : (p == 1) ? kn : vn;
    const float  sc   = (p == 0) ? 0.125f : 1.0f;   // fold 1/sqrt(DH) into q

    float acc[B];
    const float binit = (kc == 0) ? bias[col] : 0.0f;
#pragma unroll
    for (int b = 0; b < B; ++b) acc[b] = binit;

    const int k0 = kc * 64;
    for (int d = 0; d < 64; ++d) {
        const float w = W[(size_t)(k0 + d) * 1024 + col];
#pragma unroll
        for (int b = 0; b < B; ++b)
            acc[b] += x[b * 1024 + k0 + d] * w;   // wave-uniform -> s_load
    }
#pragma unroll
    for (int b = 0; b < B; ++b)
        atomicAdd(&dst[b * 1024 + col], acc[b] * sc);
}

// ---------------- Kernel B: streaming attention over the KV cache ---------
// grid 2048 = b*64 + h*4 + c. 256 threads = 4 waves; wave handles 256 t's.
// Lane layout: grp = lane>>4 picks one of 4 rows per iter; (lane&15)*4 dims.
__global__ __launch_bounds__(256) void attn_stream(
    const float* __restrict__ ext_k, const float* __restrict__ ext_v,
    const float* __restrict__ qs,
    float* __restrict__ pm, float* __restrict__ pl, float* __restrict__ pacc)
{
    const int lin  = blockIdx.x;
    const int b    = lin >> 6;
    const int h    = (lin >> 2) & 15;
    const int c    = lin & 3;
    const int tid  = threadIdx.x;
    const int wave = tid >> 6;
    const int lane = tid & 63;
    const int grp  = lane >> 4;
    const int d0   = (lane & 15) << 2;

    const float4 q4 = *(const float4*)(qs + b * 1024 + h * 64 + d0);
    const size_t base = (size_t)b * (TCTX * H * DH) + (size_t)h * DH;
    const float* kb = ext_k + base;
    const float* vb = ext_v + base;

    int t = c * CHUNK + wave * 256 + grp;
    float  m = -INFINITY, l = 0.0f;
    float4 acc = make_float4(0.f, 0.f, 0.f, 0.f);

    for (int it = 0; it < 64; ++it, t += 4) {
        const float4 k4 = *(const float4*)(kb + (size_t)t * (H * DH) + d0);
        float s = q4.x * k4.x + q4.y * k4.y + q4.z * k4.z + q4.w * k4.w;
        s += __shfl_xor(s, 1); s += __shfl_xor(s, 2);
        s += __shfl_xor(s, 4); s += __shfl_xor(s, 8);
        // s now = score of this lane's row (uniform within each 16-lane group)
        float smax = fmaxf(s, __shfl_xor(s, 16));
        smax = fmaxf(smax, __shfl_xor(smax, 32));      // max of the 4 rows
        const float mn    = fmaxf(m, smax);
        const float alpha = __expf(m - mn);            // exp(-inf)=0 on first iter
        const float e     = __expf(s - mn);
        float es = e + __shfl_xor(e, 16); es += __shfl_xor(es, 32);
        l = l * alpha + es;
        m = mn;
        const float4 v4 = *(const float4*)(vb + (size_t)t * (H * DH) + d0);
        acc.x = fmaf(acc.x, alpha, e * v4.x);
        acc.y = fmaf(acc.y, alpha, e * v4.y);
        acc.z = fmaf(acc.z, alpha, e * v4.z);
        acc.w = fmaf(acc.w, alpha, e * v4.w);
    }

    // merge the 4 row-groups (same dims live in lanes i, i^16, i^32, i^48)
    acc.x += __shfl_xor(acc.x, 16); acc.x += __shfl_xor(acc.x, 32);
    acc.y += __shfl_xor(acc.y, 16); acc.y += __shfl_xor(acc.y, 32);
    acc.z += __shfl_xor(acc.z, 16); acc.z += __shfl_xor(acc.z, 32);
    acc.w += __shfl_xor(acc.w, 16); acc.w += __shfl_xor(acc.w, 32);

    __shared__ float lm[4], ll[4], lacc[4][64];
    if (lane < 16) {
        lacc[wave][d0 + 0] = acc.x;
        lacc[wave][d0 + 1] = acc.y;
        lacc[wave][d0 + 2] = acc.z;
        lacc[wave][d0 + 3] = acc.w;
    }
    if (lane == 0) { lm[wave] = m; ll[wave] = l; }
    __syncthreads();

    if (tid < 64) {
        const float m0 = lm[0], m1 = lm[1], m2 = lm[2], m3 = lm[3];
        const float mm = fmaxf(fmaxf(m0, m1), fmaxf(m2, m3));
        const float a0 = __expf(m0 - mm), a1 = __expf(m1 - mm);
        const float a2 = __expf(m2 - mm), a3 = __expf(m3 - mm);
        const float num = a0 * lacc[0][tid] + a1 * lacc[1][tid]
                        + a2 * lacc[2][tid] + a3 * lacc[3][tid];
        pacc[lin * 64 + tid] = num;
        if (tid == 0) {
            pm[lin] = mm;
            pl[lin] = a0 * ll[0] + a1 * ll[1] + a2 * ll[2] + a3 * ll[3];
        }
    }
}

// ---------------- Kernel C: combine chunk partials + new token ------------
// grid 512 = b*16+h, 64 threads (one wave), lane = dh.
__global__ __launch_bounds__(64) void combine_ctx(
    const float* __restrict__ qs, const float* __restrict__ kn,
    const float* __restrict__ vn,
    const float* __restrict__ pm, const float* __restrict__ pl,
    const float* __restrict__ pacc,
    float* __restrict__ ctx)
{
    const int bh  = blockIdx.x;        // b*16+h
    const int d   = threadIdx.x;       // 0..63
    const int idx = bh * 64 + d;       // == b*1024 + h*64 + d

    // score of the appended token: qs is pre-scaled
    float s = qs[idx] * kn[idx];
    s += __shfl_xor(s, 1);  s += __shfl_xor(s, 2);  s += __shfl_xor(s, 4);
    s += __shfl_xor(s, 8);  s += __shfl_xor(s, 16); s += __shfl_xor(s, 32);

    const float m0 = pm[bh * 4 + 0], m1 = pm[bh * 4 + 1];
    const float m2 = pm[bh * 4 + 2], m3 = pm[bh * 4 + 3];
    float mm = fmaxf(s, fmaxf(fmaxf(m0, m1), fmaxf(m2, m3)));

    const float en = __expf(s - mm);
    float num = en * vn[idx];
    float den = en;
#pragma unroll
    for (int c = 0; c < NCHUNK; ++c) {
        const float a = __expf(pm[bh * 4 + c] - mm);
        num += a * pacc[(bh * 4 + c) * 64 + d];
        den += a * pl[bh * 4 + c];
    }
    ctx[idx] = num / den;
}

// ---------------- Kernel D: output projection (split-K, atomics) ----------
// grid (4, 16): x = 256-col chunk of D, y = K-chunk of 64 over 1024.
__global__ __launch_bounds__(256) void out_proj(
    const float* __restrict__ ctx, const float* __restrict__ Wo,
    const float* __restrict__ bo, float* __restrict__ out)
{
    const int mc = blockIdx.x;
    const int kc = blockIdx.y;
    const int mcol = mc * 256 + threadIdx.x;

    float acc[B];
    const float binit = (kc == 0) ? bo[mcol] : 0.0f;
#pragma unroll
    for (int b = 0; b < B; ++b) acc[b] = binit;

    const int k0 = kc * 64;
    for (int d = 0; d < 64; ++d) {
        const float w = Wo[(size_t)(k0 + d) * 1024 + mcol];
#pragma unroll
        for (int b = 0; b < B; ++b)
            acc[b] += ctx[b * 1024 + k0 + d] * w;   // wave-uniform -> s_load
    }
#pragma unroll
    for (int b = 0; b < B; ++b)
        atomicAdd(&out[b * 1024 + mcol], acc[b]);
}

// ---------------- launch ---------------------------------------------------
extern "C" void kernel_launch(void* const* d_in, const int* in_sizes, int n_in,
                              void* d_out, int out_size, void* d_ws, size_t ws_size,
                              hipStream_t stream)
{
    const float* x     = (const float*)d_in[0];
    const float* ext_k = (const float*)d_in[1];
    const float* ext_v = (const float*)d_in[2];
    const float* Wq    = (const float*)d_in[3];
    const float* bq    = (const float*)d_in[4];
    const float* Wk    = (const float*)d_in[5];
    const float* bk    = (const float*)d_in[6];
    const float* Wv    = (const float*)d_in[7];
    const float* bv    = (const float*)d_in[8];
    const float* Wo    = (const float*)d_in[9];
    const float* bo    = (const float*)d_in[10];
    // d_in[11] = q_pos (== T_CTX, full-context attention) -- unused

    float* ws   = (float*)d_ws;
    float* qs   = ws;                    // 32768  (q, pre-scaled by 1/8)
    float* kn   = ws + 32768;            // 32768
    float* vn   = ws + 65536;            // 32768
    float* pm   = ws + 98304;            // 2048
    float* pl   = pm + 2048;             // 2048
    float* pacc = pl + 2048;             // 131072
    float* ctx  = pacc + 131072;         // 32768

    // atomic targets must start at zero (ws/out are poisoned before each call)
    hipMemsetAsync(qs, 0, 3 * 32768 * sizeof(float), stream);
    hipMemsetAsync(d_out, 0, B * D * sizeof(float), stream);

    proj_qkv<<<dim3(12, 16), 256, 0, stream>>>(x, Wq, bq, Wk, bk, Wv, bv, qs, kn, vn);
    attn_stream<<<dim3(B * H * NCHUNK), 256, 0, stream>>>(ext_k, ext_v, qs, pm, pl, pacc);
    combine_ctx<<<dim3(B * H), 64, 0, stream>>>(qs, kn, vn, pm, pl, pacc, ctx);
    out_proj<<<dim3(4, 16), 256, 0, stream>>>(ctx, Wo, bo, (float*)d_out);
}